// Round 1
// 403.922 us; speedup vs baseline: 1.1974x; 1.1974x over previous
//
#include <hip/hip_runtime.h>

// Bilinear scatter-add, v6: single-bin-per-point + tiled register-reuse gather.
// N=500000, D=112, H=64, W=176, HW=11264 cells, ~45 points/cell.
//
// R5 post-mortem: accum=149us but TOTAL=483us -> fill (4 atomics + 4 scattered
// 4B stores per point, 2M same-line atomics on a 45KB cnt array) was ~330us.
// Accum fetched 472MB at 3.3TB/s because each feature row is demanded by 4
// independent cell-blocks (4 x 224MB demand).
//
// v6: bin each point ONCE by containing cell, entry = uint2{p, wy<<16|wx}
// (16-bit weights, err 7.6e-6). Fill: 1 atomic + 1 8B store per point; cnt
// padded to 1 counter / 64B line (no same-line atomic serialization).
// Accum: one block per 4x4 cell tile reads the 5x5 bin halo; each point's
// 448B feature row is loaded once and accumulated into up to 4 static
// register accumulators (bin loops fully unrolled -> no scratch). Feature
// demand 896MB -> 356MB. 256 thr = 2 parity groups of 112 lanes, LDS merge.

#define D     112
#define H     64
#define W     176
#define HW    (H * W)          // 11264
#define CAP   128              // mean 45.4/bin, sigma 6.7 -> ~12 sigma headroom
#define CSTR  16               // cnt stride: one counter per 64B line
#define TY    4
#define TX    4
#define GX    (W / TX)         // 44
#define GY    (H / TY)         // 16
#define NCELL (TY * TX)        // 16

__global__ __launch_bounds__(256) void fill_kernel(
    const float2* __restrict__ pos,   // [N] (x, y)
    int* __restrict__ cnt,            // [HW * CSTR], pre-zeroed
    uint2* __restrict__ bucket,       // [HW * CAP]
    int N)
{
    int p = blockIdx.x * blockDim.x + threadIdx.x;
    if (p >= N) return;

    float2 xy = pos[p];
    float xf = floorf(xy.x), yf = floorf(xy.y);
    float wx = xy.x - xf,    wy = xy.y - yf;
    int x0 = (int)xf, y0 = (int)yf;
    // defensive clamp (inputs are in [0,W-1]x[0,H-1]; this is memory safety only)
    x0 = min(max(x0, 0), W - 1);
    y0 = min(max(y0, 0), H - 1);

    int bin = y0 * W + x0;
    unsigned qw = (__float2uint_rn(wy * 65535.0f) << 16)
                |  __float2uint_rn(wx * 65535.0f);

    int i = atomicAdd(&cnt[bin * CSTR], 1);
    if (i < CAP) bucket[(size_t)bin * CAP + i] = make_uint2((unsigned)p, qw);
}

// One block per 4x4 cell tile. Cells (ty0..ty0+3, tx0..tx0+3) receive
// contributions from points binned in (ty0-1..ty0+3, tx0-1..tx0+3) = 5x5 bins.
// Point in bin (gby,gbx) with weights (wx,wy) contributes:
//   cell (gby+dy, gbx+dx) += (dy?wy:1-wy)*(dx?wx:1-wx) * feat[p]
// Bin loops are fully unrolled so accumulator indices are compile-time.
__global__ __launch_bounds__(256) void accum_kernel(
    const float* __restrict__ feat,      // [N, D]
    const int* __restrict__ cnt,
    const uint2* __restrict__ bucket,
    float* __restrict__ out)             // [H*W, D]
{
    const int tile = blockIdx.x;
    const int ty0  = (tile / GX) * TY;
    const int tx0  = (tile % GX) * TX;
    const int t    = threadIdx.x;
    const int g    = t >> 7;      // parity group 0/1
    const int tl   = t & 127;     // lane in group; feature dim = tl (tl < D)

    __shared__ uint2 se[CAP];
    __shared__ float sacc[NCELL][D];

    float acc[NCELL];
#pragma unroll
    for (int c = 0; c < NCELL; ++c) acc[c] = 0.0f;

#pragma unroll
    for (int by = -1; by < TY; ++by) {
#pragma unroll
        for (int bx = -1; bx < TX; ++bx) {
            const int gby = ty0 + by;
            const int gbx = tx0 + bx;
            int n = 0;
            if (gby >= 0 && gbx >= 0 && gbx < W)  // gby < H always (ty0+3 <= 63)
                n = min(cnt[(gby * W + gbx) * CSTR], CAP);

            if (t < n) se[t] = bucket[(size_t)(gby * W + gbx) * CAP + t];
            __syncthreads();

            if (tl < D) {
#pragma unroll 4
                for (int e = g; e < n; e += 2) {
                    uint2 en = se[e];
                    float wx = (float)(en.y & 0xffffu) * (1.0f / 65535.0f);
                    float wy = (float)(en.y >> 16)     * (1.0f / 65535.0f);
                    float f  = feat[(size_t)en.x * D + tl];
                    float ax = 1.0f - wx, ay = 1.0f - wy;
#pragma unroll
                    for (int dy = 0; dy < 2; ++dy) {
                        const int cy = by + dy;          // compile-time
                        if (cy < 0 || cy >= TY) continue;
                        float fy = dy ? wy : ay;
#pragma unroll
                        for (int dx = 0; dx < 2; ++dx) {
                            const int cx = bx + dx;      // compile-time
                            if (cx < 0 || cx >= TX) continue;
                            float fx = dx ? wx : ax;
                            acc[cy * TX + cx] = fmaf(fy * fx, f, acc[cy * TX + cx]);
                        }
                    }
                }
            }
            __syncthreads();
        }
    }

    // merge the two parity groups, then one coalesced 448B store per cell
    if (g == 1 && tl < D) {
#pragma unroll
        for (int c = 0; c < NCELL; ++c) sacc[c][tl] = acc[c];
    }
    __syncthreads();
    if (g == 0 && tl < D) {
#pragma unroll
        for (int c = 0; c < NCELL; ++c) {
            const int cy = c / TX, cx = c % TX;
            out[((size_t)(ty0 + cy) * W + (tx0 + cx)) * D + tl]
                = acc[c] + sacc[c][tl];
        }
    }
}

extern "C" void kernel_launch(void* const* d_in, const int* in_sizes, int n_in,
                              void* d_out, int out_size, void* d_ws, size_t ws_size,
                              hipStream_t stream) {
    const float2* pos = (const float2*)d_in[0];
    const float* feat = (const float*)d_in[1];
    float* out        = (float*)d_out;

    const int N = in_sizes[0] / 2;

    int* cnt      = (int*)d_ws;
    uint2* bucket = (uint2*)((char*)d_ws + (size_t)HW * CSTR * sizeof(int));
    // ws use: 11264*16*4 B (720 KB) + 11264*128*8 B (11.5 MB) = 12.3 MB

    hipMemsetAsync(cnt, 0, (size_t)HW * CSTR * sizeof(int), stream);

    fill_kernel<<<(N + 255) / 256, 256, 0, stream>>>(pos, cnt, bucket, N);
    accum_kernel<<<GY * GX, 256, 0, stream>>>(feat, cnt, bucket, out);
}